// Round 3
// baseline (239.523 us; speedup 1.0000x reference)
//
#include <hip/hip_runtime.h>
#include <hip/hip_bf16.h>

// QuantumStateEncoder: B=65536 samples, 8 qubits (256 complex amps), 2
// StronglyEntanglingLayers, fused projection + quantum sim + 2-layer MLP.
//
// Layout: one sample per 64-lane wave. Amplitude index i in [0,256):
//   i = (lane << 2) | r,  r in [0,4).
// Qubit q corresponds to bit (7-q) of i (wire 0 is MSB in the reference).
//   qubits 0..5  -> lane bits 5..0  (cross-lane via __shfl_xor)
//   qubits 6,7   -> register bits 1,0 (pure register ops)

#define DEVINL __device__ __forceinline__

// Apply shared 2x2 complex gate U=[[u00,u01],[u10,u11]] to qubit with bit
// position P of the amplitude index.
template<int P>
DEVINL void rot(float2 a[4], const float4* gp, int lane) {
  float4 g0 = gp[0], g1 = gp[1];
  float2 u00 = {g0.x, g0.y}, u01 = {g0.z, g0.w};
  float2 u10 = {g1.x, g1.y}, u11 = {g1.z, g1.w};
  if constexpr (P >= 2) {
    const int m = 1 << (P - 2);
    const int bset = (lane >> (P - 2)) & 1;
    float2 cA, cB;
    cA.x = bset ? u11.x : u00.x;  cA.y = bset ? u11.y : u00.y;
    cB.x = bset ? u10.x : u01.x;  cB.y = bset ? u10.y : u01.y;
#pragma unroll
    for (int r = 0; r < 4; ++r) {
      float px = __shfl_xor(a[r].x, m, 64);
      float py = __shfl_xor(a[r].y, m, 64);
      float nx = cA.x * a[r].x - cA.y * a[r].y + cB.x * px - cB.y * py;
      float ny = cA.x * a[r].y + cA.y * a[r].x + cB.x * py + cB.y * px;
      a[r].x = nx; a[r].y = ny;
    }
  } else {
    const int m = 1 << P;
#pragma unroll
    for (int r = 0; r < 4; ++r) {
      if ((r & m) == 0) {
        float2 a0 = a[r], a1 = a[r | m];
        a[r].x     = u00.x*a0.x - u00.y*a0.y + u01.x*a1.x - u01.y*a1.y;
        a[r].y     = u00.x*a0.y + u00.y*a0.x + u01.x*a1.y + u01.y*a1.x;
        a[r | m].x = u10.x*a0.x - u10.y*a0.y + u11.x*a1.x - u11.y*a1.y;
        a[r | m].y = u10.x*a0.y + u10.y*a0.x + u11.x*a1.y + u11.y*a1.x;
      }
    }
  }
}

// CNOT with control bit position PC, target bit position PT (of amp index).
template<int PC, int PT>
DEVINL void cnot(float2 a[4], int lane) {
  if constexpr (PC >= 2 && PT >= 2) {
    // both in lane bits: unconditional shfl, select where control=1
    const int tm = 1 << (PT - 2);
    const bool ctrl = (lane >> (PC - 2)) & 1;
#pragma unroll
    for (int r = 0; r < 4; ++r) {
      float px = __shfl_xor(a[r].x, tm, 64);
      float py = __shfl_xor(a[r].y, tm, 64);
      if (ctrl) { a[r].x = px; a[r].y = py; }
    }
  } else if constexpr (PC >= 2) {
    // control in lane bits, target in register bits: predicated reg swap
    const int tm = 1 << PT;
    const bool ctrl = (lane >> (PC - 2)) & 1;
    if (ctrl) {
#pragma unroll
      for (int r = 0; r < 4; ++r)
        if ((r & tm) == 0) { float2 t = a[r]; a[r] = a[r | tm]; a[r | tm] = t; }
    }
  } else if constexpr (PT >= 2) {
    // control in register bits, target in lane bits: shfl-swap regs w/ ctrl=1
    const int tm = 1 << (PT - 2);
#pragma unroll
    for (int r = 0; r < 4; ++r) {
      if (r & (1 << PC)) {
        a[r].x = __shfl_xor(a[r].x, tm, 64);
        a[r].y = __shfl_xor(a[r].y, tm, 64);
      }
    }
  } else {
    // both in register bits
#pragma unroll
    for (int r = 0; r < 4; ++r)
      if ((r & (1 << PC)) && !(r & (1 << PT))) {
        float2 t = a[r]; a[r] = a[r | (1 << PT)]; a[r | (1 << PT)] = t;
      }
  }
}

// Precompute the 16 shared Rot matrices (PennyLane Rot = RZ(om)RY(th)RZ(phi))
// into ws: gate g -> 2 float4 = [u00.re,u00.im,u01.re,u01.im],[u10...,u11...]
__global__ void prep_gates(const float* __restrict__ qw, float* __restrict__ ws) {
  int g = threadIdx.x;
  if (g >= 16) return;
  float phi = qw[g*3 + 0], th = qw[g*3 + 1], om = qw[g*3 + 2];
  float s, c, sp, cp, sm, cm;
  sincosf(0.5f * th, &s, &c);
  sincosf(0.5f * (phi + om), &sp, &cp);   // ep = (cp, -sp)
  sincosf(0.5f * (phi - om), &sm, &cm);   // em = (cm, -sm)
  float4* G = (float4*)ws;
  // u00 = ep*c            u01 = -conj(em)*s
  G[g*2 + 0] = make_float4(cp * c, -sp * c, -cm * s, -sm * s);
  // u10 = em*s            u11 = conj(ep)*c
  G[g*2 + 1] = make_float4(cm * s, -sm * s, cp * c, sp * c);
}

__global__ __launch_bounds__(256)
void qnet_main(const float* __restrict__ x, const float* __restrict__ Wp,
               const float* __restrict__ bp, const float4* __restrict__ G,
               const float* __restrict__ W1, const float* __restrict__ b1,
               const float* __restrict__ W2, const float* __restrict__ b2,
               float* __restrict__ out, int B) {
  __shared__ __align__(16) float sh_h[256];
  const int tid = threadIdx.x;
  const int wid = tid >> 6, lane = tid & 63;
  const int b = blockIdx.x * 4 + wid;

  float h = 0.f;
  if (b < B) {
    // ---- input projection: angles[q] = sum_k x[b,k]*Wp[q,k] + bp[q] ----
    const int q = lane & 7, g = lane >> 3;
    const float* xr = x + (size_t)b * 17;
    float partial = xr[g] * Wp[q*17 + g] + xr[g + 8] * Wp[q*17 + g + 8];
    if (g == 0) partial += xr[16] * Wp[q*17 + 16];
    partial += __shfl_xor(partial, 8, 64);
    partial += __shfl_xor(partial, 16, 64);
    partial += __shfl_xor(partial, 32, 64);
    float ang = partial + bp[q];
    float sv, cv;
    sincosf(0.5f * ang, &sv, &cv);
    float cq[8], sq[8];
#pragma unroll
    for (int k = 0; k < 8; ++k) {
      cq[k] = __shfl(cv, k, 64);
      sq[k] = __shfl(sv, k, 64);
    }

    // ---- AngleEmbedding RX(a_q): product state ----
    // factor f_q(0) = cq, f_q(1) = (0, -sq)
    float re = 1.f, im = 0.f;
#pragma unroll
    for (int k = 0; k < 6; ++k) {           // qubits 0..5 live in lane bits 5..0
      const int bit = (lane >> (5 - k)) & 1;
      float nre = bit ? im * sq[k] : re * cq[k];
      float nim = bit ? -re * sq[k] : im * cq[k];
      re = nre; im = nim;
    }
    float c67 = cq[6]*cq[7], c6s7 = cq[6]*sq[7], s6c7 = sq[6]*cq[7], s67 = sq[6]*sq[7];
    float2 a[4];
    a[0] = make_float2( re * c67,   im * c67);
    a[1] = make_float2( im * c6s7, -re * c6s7);
    a[2] = make_float2( im * s6c7, -re * s6c7);
    a[3] = make_float2(-re * s67,  -im * s67);

    // ---- StronglyEntanglingLayers (qubit q <-> bit P = 7-q) ----
    // layer 0: Rots, then CNOT(q, q+1 mod 8)
    rot<7>(a, G + 0*2, lane);  rot<6>(a, G + 1*2, lane);
    rot<5>(a, G + 2*2, lane);  rot<4>(a, G + 3*2, lane);
    rot<3>(a, G + 4*2, lane);  rot<2>(a, G + 5*2, lane);
    rot<1>(a, G + 6*2, lane);  rot<0>(a, G + 7*2, lane);
    cnot<7,6>(a, lane); cnot<6,5>(a, lane); cnot<5,4>(a, lane); cnot<4,3>(a, lane);
    cnot<3,2>(a, lane); cnot<2,1>(a, lane); cnot<1,0>(a, lane); cnot<0,7>(a, lane);
    // layer 1: Rots, then CNOT(q, q+2 mod 8)
    rot<7>(a, G +  8*2, lane); rot<6>(a, G +  9*2, lane);
    rot<5>(a, G + 10*2, lane); rot<4>(a, G + 11*2, lane);
    rot<3>(a, G + 12*2, lane); rot<2>(a, G + 13*2, lane);
    rot<1>(a, G + 14*2, lane); rot<0>(a, G + 15*2, lane);
    cnot<7,5>(a, lane); cnot<6,4>(a, lane); cnot<5,3>(a, lane); cnot<4,2>(a, lane);
    cnot<3,1>(a, lane); cnot<2,0>(a, lane); cnot<1,7>(a, lane); cnot<0,6>(a, lane);

    // ---- <Z_q> expectations ----
    float p0 = a[0].x*a[0].x + a[0].y*a[0].y;
    float p1 = a[1].x*a[1].x + a[1].y*a[1].y;
    float p2 = a[2].x*a[2].x + a[2].y*a[2].y;
    float p3 = a[3].x*a[3].x + a[3].y*a[3].y;
    float ps = p0 + p1 + p2 + p3;
    float zq[8];
#pragma unroll
    for (int k = 0; k < 6; ++k)
      zq[k] = (((lane >> (5 - k)) & 1) ? -ps : ps);
    zq[6] = (p0 + p1) - (p2 + p3);
    zq[7] = (p0 + p2) - (p1 + p3);
#pragma unroll
    for (int m = 1; m <= 32; m <<= 1) {
#pragma unroll
      for (int k = 0; k < 8; ++k)
        zq[k] += __shfl_xor(zq[k], m, 64);
    }

    // ---- MLP layer 1: h[lane] = relu(b1 + sum_q z_q * W1[lane,q]) ----
    const float4* w1r = (const float4*)(W1 + lane * 8);
    float4 wA = w1r[0], wB = w1r[1];
    float acc = b1[lane];
    acc += zq[0]*wA.x + zq[1]*wA.y + zq[2]*wA.z + zq[3]*wA.w;
    acc += zq[4]*wB.x + zq[5]*wB.y + zq[6]*wB.z + zq[7]*wB.w;
    h = fmaxf(acc, 0.f);
  }

  sh_h[tid] = h;   // sh_h[wid*64 + lane]
  __syncthreads();

  // ---- MLP layer 2: out[b,j] = tanh(b2[j] + sum_l h[l] * W2[j,l]) ----
  if (tid < 128) {
    const int s = tid >> 5, j = tid & 31;
    const int bo = blockIdx.x * 4 + s;
    if (bo < B) {
      const float4* w2r = (const float4*)(W2 + j * 64);
      const float4* hh  = (const float4*)(sh_h + s * 64);
      float acc = b2[j];
#pragma unroll
      for (int i4 = 0; i4 < 16; ++i4) {
        float4 w = w2r[i4], hv = hh[i4];
        acc += w.x*hv.x + w.y*hv.y + w.z*hv.z + w.w*hv.w;
      }
      out[(size_t)bo * 32 + j] = tanhf(acc);
    }
  }
}

extern "C" void kernel_launch(void* const* d_in, const int* in_sizes, int n_in,
                              void* d_out, int out_size, void* d_ws, size_t ws_size,
                              hipStream_t stream) {
  const float* x  = (const float*)d_in[0];
  const float* Wp = (const float*)d_in[1];
  const float* bp = (const float*)d_in[2];
  const float* qw = (const float*)d_in[3];
  const float* W1 = (const float*)d_in[4];
  const float* b1 = (const float*)d_in[5];
  const float* W2 = (const float*)d_in[6];
  const float* b2 = (const float*)d_in[7];
  float* out = (float*)d_out;
  const int B = in_sizes[0] / 17;   // 65536

  prep_gates<<<1, 64, 0, stream>>>(qw, (float*)d_ws);
  qnet_main<<<(B + 3) / 4, 256, 0, stream>>>(x, Wp, bp, (const float4*)d_ws,
                                             W1, b1, W2, b2, out, B);
}

// Round 8
// 112.390 us; speedup vs baseline: 2.1312x; 2.1312x over previous
//
#include <hip/hip_runtime.h>
#include <hip/hip_bf16.h>
#include <math.h>

// QuantumStateEncoder — algebraic collapse version.
// z_q = <psi1| C1' R2' C2' Z_q C2 R2 C1 |psi1>, psi1 = prod_j R1_j RX(a_j)|0>.
//  - C2' Z_q C2  -> Z-string on qubit set S_q            (Clifford, precomputed)
//  - R2' (Zstr) R2 -> tensor prod of (n_j . sigma)       (n_j from prep kernel)
//  - C1' (Pauli string) C1 -> Pauli string, sign +-1     (constexpr symplectic algebra)
//  - <sigma_a>_{psi1,j} = Bloch r_{j,a} = -sin(a_j)*AY_a + cos(a_j)*AZ_a
// => z_q = sum_t coef_t * prod_j r_{j,code(t,j)}  (288 terms, codes compile-time)
// Then per-lane fused MLP: out = tanh(W2 relu(W1 z + b1) + b2).

#define DEVINL __device__ __forceinline__

// ---------- compile-time Pauli algebra (P = i^ph * X^x * Z^z) ----------
struct Pau { unsigned x, z; int ph; };
constexpr int pcnt8(unsigned v){ int c=0; for(int i=0;i<8;++i) c+=(v>>i)&1; return c; }
constexpr Pau pmul(Pau a, Pau b){
  return Pau{a.x^b.x, a.z^b.z, (a.ph + b.ph + 2*pcnt8(a.z & b.x)) & 3};
}
// C1-conjugated generators (ring CNOT(q,q+1), q=0..7 applied ascending):
//   X_j -> X_j X_{j+1} (j<7), X_7 -> X_7 X_0 X_1
//   Z_j -> Z_0..Z_j (j>0),   Z_0 -> Z_1..Z_7
//   Y_j = i X_j Z_j  (phases via pmul)
constexpr Pau conjP(int j, int a){
  Pau X{ j<7 ? ((1u<<j)|(1u<<(j+1))) : 0x83u, 0u, 0 };
  Pau Z{ 0u, j>0 ? ((2u<<j)-1u) : 0xFEu, 0 };
  if (a==0) return X;
  if (a==2) return Z;
  Pau y = pmul(X, Z);
  return Pau{y.x, y.z, (y.ph+1)&3};
}
// Qubit sets S_q after pulling Z_q back through ring 2 (CNOT(q,q+2)):
constexpr unsigned SQM[8] = {0x54,0xA8,0x05,0x0A,0x15,0x2A,0x55,0xAA};
constexpr int TPREF[9]   = {0,27,54,63,72,99,126,207,288};   // 3^|S_q| prefix

struct TTab { unsigned char mx[288], my[288], mz[288]; signed char sg[288]; };
constexpr TTab gen_tt(){
  TTab T{};
  int t=0;
  for (int q=0;q<8;++q){
    int sup[8]={}; int m=0;
    for (int j=0;j<8;++j) if ((SQM[q]>>j)&1) sup[m++]=j;
    int nt=1; for (int i=0;i<m;++i) nt*=3;
    for (int a=0;a<nt;++a){
      Pau P{0u,0u,0}; int rem=a;
      for (int i=0;i<m;++i){ P = pmul(P, conjP(sup[i], rem%3)); rem/=3; }
      unsigned y = P.x & P.z;                 // XZ = -iY qubits
      int tau = (P.ph + 3*pcnt8(y)) & 3;      // total i-power; must be 0 or 2
      T.mx[t]=(unsigned char)(P.x & ~P.z);
      T.my[t]=(unsigned char)y;
      T.mz[t]=(unsigned char)(P.z & ~P.x);
      T.sg[t]=(signed char)(tau==0 ? 1 : -1);
      ++t;
    }
  }
  return T;
}
constexpr TTab TT = gen_tt();

// ---------- prep: per-qubit Bloch maps + 288 term coefficients ----------
struct cpx { float r, i; };
DEVINL cpx cmul(cpx a, cpx b){ return {a.r*b.r - a.i*b.i, a.r*b.i + a.i*b.r}; }
DEVINL cpx cconj(cpx a){ return {a.r, -a.i}; }
DEVINL cpx cadd(cpx a, cpx b){ return {a.r+b.r, a.i+b.i}; }

DEVINL void buildR(const float* qw3, cpx R[2][2]){
  float phi=qw3[0], th=qw3[1], om=qw3[2], s,c,sp,cp,sm,cm;
  sincosf(0.5f*th,&s,&c);
  sincosf(0.5f*(phi+om),&sp,&cp);   // ep = cp - i sp
  sincosf(0.5f*(phi-om),&sm,&cm);   // em = cm - i sm
  R[0][0]={cp*c,-sp*c}; R[0][1]={-cm*s,-sm*s};
  R[1][0]={cm*s,-sm*s}; R[1][1]={cp*c, sp*c};
}
// H = R^dag * S * R
DEVINL void conjH(const cpx R[2][2], const cpx S[2][2], cpx H[2][2]){
  cpx M[2][2];
  for (int i=0;i<2;++i) for (int j=0;j<2;++j)
    M[i][j] = cadd(cmul(S[i][0],R[0][j]), cmul(S[i][1],R[1][j]));
  for (int i=0;i<2;++i) for (int j=0;j<2;++j)
    H[i][j] = cadd(cmul(cconj(R[0][i]),M[0][j]), cmul(cconj(R[1][i]),M[1][j]));
}

// ws layout: [0..47] per-qubit {AYx,AYy,AYz,AZx,AZy,AZz}; [48..335] coefs
__global__ void prep_kernel(const float* __restrict__ qw, float* __restrict__ ws){
  __shared__ float n_sh[8][3];
  const int tid = threadIdx.x;
  if (tid < 8){
    const int q = tid;
    cpx R1[2][2], R2[2][2], H[2][2];
    buildR(qw + q*3,      R1);     // layer 0 gate
    buildR(qw + 24 + q*3, R2);     // layer 1 gate
    const cpx SX[2][2] = {{{0,0},{1,0}},{{1,0},{0,0}}};
    const cpx SY[2][2] = {{{0,0},{0,-1}},{{0,1},{0,0}}};
    const cpx SZ[2][2] = {{{1,0},{0,0}},{{0,0},{-1,0}}};
    conjH(R1,SX,H); ws[q*6+0] = -H[0][1].i; ws[q*6+3] = H[0][0].r;
    conjH(R1,SY,H); ws[q*6+1] = -H[0][1].i; ws[q*6+4] = H[0][0].r;
    conjH(R1,SZ,H); ws[q*6+2] = -H[0][1].i; ws[q*6+5] = H[0][0].r;
    conjH(R2,SZ,H);
    n_sh[q][0] = H[0][1].r;        // n_x
    n_sh[q][1] = -H[0][1].i;       // n_y
    n_sh[q][2] = H[0][0].r;        // n_z
  }
  __syncthreads();
  if (tid < 288){
    int q = 0;
    while (tid >= TPREF[q+1]) ++q;
    int rem = tid - TPREF[q];
    float coef = (float)TT.sg[tid];
    unsigned m = SQM[q];
    while (m){
      int j = __ffs(m) - 1; m &= m - 1;
      coef *= n_sh[j][rem % 3];
      rem /= 3;
    }
    ws[48 + tid] = coef;
  }
}

// ---------- main: one sample per lane ----------
__global__ __launch_bounds__(256)
void qnet_pauli(const float* __restrict__ x, const float* __restrict__ Wp,
                const float* __restrict__ bp, const float* __restrict__ ws,
                const float* __restrict__ W1, const float* __restrict__ b1,
                const float* __restrict__ W2, const float* __restrict__ b2,
                float* __restrict__ out, int B){
  __shared__ float sh_x[256*17];
  const int tid = threadIdx.x;
  const int b   = blockIdx.x*256 + tid;
  // coalesced stage of this block's x rows
  const int base = blockIdx.x*256*17;
  const int lim  = B*17 - base;
#pragma unroll
  for (int i = 0; i < 17; ++i){
    int o = i*256 + tid;
    if (o < lim) sh_x[o] = x[base + o];
  }
  __syncthreads();
  if (b >= B) return;

  float xv[17];
#pragma unroll
  for (int k=0;k<17;++k) xv[k] = sh_x[tid*17 + k];

  // Bloch vectors per qubit
  float rx[8], ry[8], rz[8];
#pragma unroll
  for (int q=0;q<8;++q){
    float ang = bp[q];
#pragma unroll
    for (int k=0;k<17;++k) ang = fmaf(xv[k], Wp[q*17+k], ang);
    float sa, ca;
    __sincosf(ang, &sa, &ca);
    rx[q] = ca*ws[q*6+3] - sa*ws[q*6+0];
    ry[q] = ca*ws[q*6+4] - sa*ws[q*6+1];
    rz[q] = ca*ws[q*6+5] - sa*ws[q*6+2];
  }

  // z_q = sum_t coef_t * prod_j r_{j,code}
  const float* cf = ws + 48;
  float zz[8];
#pragma unroll
  for (int q=0;q<8;++q){
    float acc = 0.f;
#pragma unroll
    for (int t=TPREF[q]; t<TPREF[q+1]; ++t){
      float p = cf[t];
#pragma unroll
      for (int j=0;j<8;++j){
        if (TT.mx[t] & (1u<<j)) p *= rx[j];
        if (TT.my[t] & (1u<<j)) p *= ry[j];
        if (TT.mz[t] & (1u<<j)) p *= rz[j];
      }
      acc += p;
    }
    zz[q] = acc;
  }

  // MLP1: h = relu(W1 z + b1)
  float h[64];
#pragma unroll
  for (int l=0;l<64;++l){
    float acc = b1[l];
#pragma unroll
    for (int q=0;q<8;++q) acc = fmaf(zz[q], W1[l*8+q], acc);
    h[l] = fmaxf(acc, 0.f);
  }

  // MLP2: out = tanh(W2 h + b2)
  float* op = out + (size_t)b*32;
#pragma unroll 4
  for (int j=0;j<32;++j){
    float acc = b2[j];
#pragma unroll
    for (int l=0;l<64;++l) acc = fmaf(h[l], W2[j*64+l], acc);
    float e = __expf(2.f*acc);
    op[j] = 1.f - 2.f/(e + 1.f);
  }
}

extern "C" void kernel_launch(void* const* d_in, const int* in_sizes, int n_in,
                              void* d_out, int out_size, void* d_ws, size_t ws_size,
                              hipStream_t stream) {
  const float* x  = (const float*)d_in[0];
  const float* Wp = (const float*)d_in[1];
  const float* bp = (const float*)d_in[2];
  const float* qw = (const float*)d_in[3];
  const float* W1 = (const float*)d_in[4];
  const float* b1 = (const float*)d_in[5];
  const float* W2 = (const float*)d_in[6];
  const float* b2 = (const float*)d_in[7];
  float* out = (float*)d_out;
  const int B = in_sizes[0] / 17;   // 65536

  prep_kernel<<<1, 288, 0, stream>>>(qw, (float*)d_ws);
  qnet_pauli<<<(B + 255)/256, 256, 0, stream>>>(x, Wp, bp, (const float*)d_ws,
                                                W1, b1, W2, b2, out, B);
}